// Round 2
// baseline (92.284 us; speedup 1.0000x reference)
//
#include <hip/hip_runtime.h>
#include <hip/hip_bf16.h>

// Problem constants (fixed by the reference setup)
#define B_  16
#define C_  64
#define H_  64
#define W_  64
#define O_  64
#define EPS 1e-6f
#define SLOPE 0.01f

typedef __bf16  bf16x8 __attribute__((ext_vector_type(8)));
typedef float   f32x4  __attribute__((ext_vector_type(4)));

// ---- LDS layout (bytes) ----
// Weights: [tap(9)][p(2)][o(64)][c2(32)+8 pad] bf16, row stride 40 bf16 = 80 B
//   -> b128 fragment reads: lanes stride 20 dwords -> 2-way banks (free)
#define WLDS_OFF 0
#define WLDS_SZ  92160          // 18 * 64 * 80
// x tile: [r(4)][w(64)][p(2)][c2(32)] bf16, row stride 72 bf16 = 144 B (16B aligned)
//   -> b128 fragment reads: lanes stride 36 dwords -> 2-way banks (free)
#define XT_OFF   92160
#define XT_SZ    36864          // 4 * 64 * 144
#define PMIN_OFF 129024         // float[2][4][64]
#define PMAX_OFF 131072         // float[2][4][64]
#define SINV_OFF 133120         // float[2][2][64]  1/(s+eps) per (row,parity,w)
#define SEPS_OFF 134144         // float[2][2][64]  (s+eps)
#define SMEM_SZ  135168

__device__ __forceinline__ unsigned short f2bf(float f) {
  unsigned u = __float_as_uint(f);         // fp32 -> bf16 RNE
  u += 0x7fffu + ((u >> 16) & 1u);
  return (unsigned short)(u >> 16);
}

// Transform W[o][c][j][i] (fp32 global) -> bf16 Wt[((tap*2+p)*64+o)*40 + c2],
// tap = i*3+j. einsum 'bcijhw,ocji' => tap (i,j) multiplies W[o][c][j][i].
__global__ void wtransform_kernel(const float* __restrict__ Wsrc,
                                  unsigned short* __restrict__ Wt) {
  int idx = blockIdx.x * 256 + threadIdx.x;      // 64*64*9 = 36864 exact
  if (idx >= O_ * C_ * 9) return;
  int i = idx % 3;
  int j = (idx / 3) % 3;
  int c = (idx / 9) % C_;
  int o = idx / (9 * C_);
  int tap = i * 3 + j;
  Wt[((tap * 2 + (c & 1)) * 64 + o) * 40 + (c >> 1)] = f2bf(Wsrc[idx]);
}

__device__ __forceinline__ int clampi(int v, int lo, int hi) {
  return v < lo ? lo : (v > hi ? hi : v);
}

// One block = one (b, h0) pair of output rows. M=64 (all o), N=128 (2 rows x 64 w).
// 4 waves: wave wv -> output row hh = wv>>1, o-half mt2 = wv&1 (32 o x 64 w tile).
__launch_bounds__(256, 1)
__global__ void conv_main_kernel(const float* __restrict__ x,
                                 const unsigned short* __restrict__ Wt,
                                 const float* __restrict__ bias,
                                 float* __restrict__ out) {
  extern __shared__ char smem[];
  const int tid  = threadIdx.x;
  const int lane = tid & 63;
  const int wv   = tid >> 6;
  const int b    = blockIdx.x >> 5;
  const int h0   = (blockIdx.x & 31) << 1;

  // ---- stage weights: straight 16B copy of pre-transformed global buffer ----
  {
    const uint4* src = (const uint4*)Wt;
    uint4* dst = (uint4*)(smem + WLDS_OFF);
    for (int k = tid; k < WLDS_SZ / 16; k += 256) dst[k] = src[k];
  }

  // ---- stage x tile rows h0-1..h0+2 (replicate-clamped) into [r][w][p][c2] ----
  // Each thread: fixed w = tid&63 (coalesced fp32 global reads), 8 groups of
  // (r, p, m) where m = c2-octet; converts 8 channels to bf16 -> ds_write_b128.
  {
    const int w = tid & 63;
    const int set = tid >> 6;
    for (int k = 0; k < 8; ++k) {
      const int g = set * 8 + k;       // 0..31
      const int r = g >> 3;
      const int p = (g >> 2) & 1;
      const int m = g & 3;
      const int hr = clampi(h0 - 1 + r, 0, H_ - 1);
      unsigned d[4];
      #pragma unroll
      for (int e = 0; e < 4; ++e) {
        const int c2a = m * 8 + 2 * e;
        const unsigned lo = f2bf(x[((b * C_ + (2 * c2a + p)) * H_ + hr) * W_ + w]);
        const unsigned hi = f2bf(x[((b * C_ + (2 * (c2a + 1) + p)) * H_ + hr) * W_ + w]);
        d[e] = lo | (hi << 16);
      }
      *(uint4*)(smem + XT_OFF + (r * 64 + w) * 144 + p * 64 + m * 16) =
          make_uint4(d[0], d[1], d[2], d[3]);
    }
  }
  __syncthreads();

  // ---- s-pass 1: per (r, w, parity) min/max over 32 channels (bf16-rounded) --
  {
    const int r = tid >> 6, w = tid & 63;
    const char* rowp = smem + XT_OFF + (r * 64 + w) * 144;
    float* pmin = (float*)(smem + PMIN_OFF);
    float* pmax = (float*)(smem + PMAX_OFF);
    #pragma unroll
    for (int p = 0; p < 2; ++p) {
      float mn = 3.4e38f, mx = -3.4e38f;
      #pragma unroll
      for (int k4 = 0; k4 < 4; ++k4) {
        const uint4 v = *(const uint4*)(rowp + p * 64 + k4 * 16);
        const unsigned dd[4] = {v.x, v.y, v.z, v.w};
        #pragma unroll
        for (int e = 0; e < 4; ++e) {
          const float a = __uint_as_float(dd[e] << 16);        // even half
          const float c = __uint_as_float(dd[e] & 0xffff0000u);// odd half
          mn = fminf(mn, fminf(a, c));
          mx = fmaxf(mx, fmaxf(a, c));
        }
      }
      pmin[(p * 4 + r) * 64 + w] = mn;
      pmax[(p * 4 + r) * 64 + w] = mx;
    }
  }
  __syncthreads();

  // ---- s-pass 2: 3x3 window reduce -> s+eps and 1/(s+eps) per (row, parity, w)
  {
    const int hh = tid >> 7, p = (tid >> 6) & 1, w = tid & 63;
    const float* pmin = (const float*)(smem + PMIN_OFF);
    const float* pmax = (const float*)(smem + PMAX_OFF);
    float mn = 3.4e38f, mx = -3.4e38f;
    #pragma unroll
    for (int r = 0; r < 3; ++r) {
      #pragma unroll
      for (int dw = -1; dw <= 1; ++dw) {
        const int wc = clampi(w + dw, 0, W_ - 1);
        mn = fminf(mn, pmin[(p * 4 + (hh + r)) * 64 + wc]);
        mx = fmaxf(mx, pmax[(p * 4 + (hh + r)) * 64 + wc]);
      }
    }
    const float sv = (mx - mn) + EPS;
    ((float*)(smem + SEPS_OFF))[(hh * 2 + p) * 64 + w] = sv;
    ((float*)(smem + SINV_OFF))[(hh * 2 + p) * 64 + w] = 1.0f / sv;
  }
  __syncthreads();

  // ---- MFMA main loop: 9 taps x 2 parities, K=32 channels per step ----
  const int hh  = wv >> 1;          // output row within tile
  const int mt2 = wv & 1;           // o-half
  const int l15 = lane & 15;
  const int q   = lane >> 4;

  const f32x4 zero = {0.0f, 0.0f, 0.0f, 0.0f};
  f32x4 acc[2][2][4];
  #pragma unroll
  for (int p = 0; p < 2; ++p)
    #pragma unroll
    for (int mt = 0; mt < 2; ++mt)
      #pragma unroll
      for (int nt = 0; nt < 4; ++nt) acc[p][mt][nt] = zero;

  for (int tap = 0; tap < 9; ++tap) {
    const int i = tap / 3, j = tap % 3;
    const int xr = hh + i;                          // x-tile row
    #pragma unroll
    for (int p = 0; p < 2; ++p) {
      bf16x8 af[2], bfr[4];
      #pragma unroll
      for (int mt = 0; mt < 2; ++mt)               // A[m=o][k=c2], m=lane&15
        af[mt] = *(const bf16x8*)(smem + WLDS_OFF +
                   ((tap * 2 + p) * 64 + mt2 * 32 + mt * 16 + l15) * 80 + q * 16);
      #pragma unroll
      for (int nt = 0; nt < 4; ++nt) {             // B[k=c2][n=w], n=lane&15
        const int wc = clampi(nt * 16 + l15 + j - 1, 0, W_ - 1);
        bfr[nt] = *(const bf16x8*)(smem + XT_OFF + (xr * 64 + wc) * 144 + p * 64 + q * 16);
      }
      #pragma unroll
      for (int mt = 0; mt < 2; ++mt)
        #pragma unroll
        for (int nt = 0; nt < 4; ++nt)
          acc[p][mt][nt] = __builtin_amdgcn_mfma_f32_16x16x32_bf16(
              af[mt], bfr[nt], acc[p][mt][nt], 0, 0, 0);
    }
  }

  // ---- epilogue: combine parities, bias, leaky-relu, re-scale, store fp32 ----
  // D layout: col(w) = lane&15, row(o) = (lane>>4)*4 + reg
  const float* sinv = (const float*)(smem + SINV_OFF);
  const float* seps = (const float*)(smem + SEPS_OFF);
  #pragma unroll
  for (int mt = 0; mt < 2; ++mt) {
    #pragma unroll
    for (int reg = 0; reg < 4; ++reg) {
      const int o = mt2 * 32 + mt * 16 + q * 4 + reg;
      const float bv = bias[o];
      #pragma unroll
      for (int nt = 0; nt < 4; ++nt) {
        const int wpx = nt * 16 + l15;
        float v = acc[0][mt][nt][reg] * sinv[(hh * 2 + 0) * 64 + wpx]
                + acc[1][mt][nt][reg] * sinv[(hh * 2 + 1) * 64 + wpx]
                + bv;
        v = v >= 0.0f ? v : SLOPE * v;
        v *= seps[(hh * 2 + (o & 1)) * 64 + wpx];
        out[((b * O_ + o) * H_ + (h0 + hh)) * W_ + wpx] = v;
      }
    }
  }
}

extern "C" void kernel_launch(void* const* d_in, const int* in_sizes, int n_in,
                              void* d_out, int out_size, void* d_ws, size_t ws_size,
                              hipStream_t stream) {
  // fp32 dataset (reference is float32 throughout): xx, W, b fp32; output fp32.
  const float* x    = (const float*)d_in[0];
  const float* Wsrc = (const float*)d_in[1];
  const float* bias = (const float*)d_in[2];
  float* out = (float*)d_out;
  unsigned short* Wt = (unsigned short*)d_ws;   // 92,160 B scratch (bf16 weights)

  wtransform_kernel<<<144, 256, 0, stream>>>(Wsrc, Wt);

  (void)hipFuncSetAttribute((const void*)conv_main_kernel,
                            hipFuncAttributeMaxDynamicSharedMemorySize, SMEM_SZ);
  conv_main_kernel<<<512, 256, SMEM_SZ, stream>>>(x, Wt, bias, out);
}

// Round 3
// 82.437 us; speedup vs baseline: 1.1195x; 1.1195x over previous
//
#include <hip/hip_runtime.h>
#include <hip/hip_bf16.h>

// Problem constants (fixed by the reference setup)
#define B_  16
#define C_  64
#define H_  64
#define W_  64
#define O_  64
#define EPS 1e-6f
#define SLOPE 0.01f

typedef __bf16  bf16x8 __attribute__((ext_vector_type(8)));
typedef float   f32x4  __attribute__((ext_vector_type(4)));

// ---- static LDS layout (bytes) ----
// x tile: [r(4)][w(64)][p(2)][c2(32)] bf16, row stride 144 B (16B aligned)
#define XT_OFF   0
#define XT_SZ    36864          // 4 * 64 * 144
#define PMIN_OFF 36864          // float[p(2)][r(4)][w(64)]
#define PMAX_OFF 38912
#define SINV_OFF 40960          // float[hh(2)][p(2)][w(64)]  1/(s+eps)
#define SEPS_OFF 42000          // padded to dword: use 41984
#undef  SEPS_OFF
#define SEPS_OFF 41984
#define SMEM_SZ  43008

__device__ __forceinline__ unsigned short f2bf(float f) {
  unsigned u = __float_as_uint(f);         // fp32 -> bf16 RNE
  u += 0x7fffu + ((u >> 16) & 1u);
  return (unsigned short)(u >> 16);
}

__device__ __forceinline__ int clampi(int v, int lo, int hi) {
  return v < lo ? lo : (v > hi ? hi : v);
}

// Transform W[o][c][j][i] (fp32) -> bf16 Wt[((tap*2+p)*64 + o)*32 + c2],
// tap = i*3+j (einsum 'bcijhw,ocji': tap (i,j) uses W[o][c][j][i]).
// Per-wave A-frag load becomes one coalesced 1KB global_load_dwordx4:
//   addr = ((tap*2+p)*64 + o0 + l15)*64B + q*16B
__global__ void wtransform_kernel(const float* __restrict__ Wsrc,
                                  unsigned short* __restrict__ Wt) {
  int idx = blockIdx.x * 256 + threadIdx.x;      // 64*64*9 = 36864 exact
  if (idx >= O_ * C_ * 9) return;
  int i = idx % 3;
  int j = (idx / 3) % 3;
  int c = (idx / 9) % C_;
  int o = idx / (9 * C_);
  int tap = i * 3 + j;
  Wt[((tap * 2 + (c & 1)) * 64 + o) * 32 + (c >> 1)] = f2bf(Wsrc[idx]);
}

// One block = one (b, h0) pair of output rows. 4 waves; wave wv owns o-slice
// o0 = wv*16 and computes 16o x (2 rows x 64 w). Weights live in VGPRs.
__launch_bounds__(256, 3)
__global__ void conv_main_kernel(const float* __restrict__ x,
                                 const unsigned short* __restrict__ Wt,
                                 const float* __restrict__ bias,
                                 float* __restrict__ out) {
  __shared__ char smem[SMEM_SZ];
  const int tid  = threadIdx.x;
  const int lane = tid & 63;
  const int wv   = tid >> 6;
  const int b    = blockIdx.x >> 5;
  const int h0   = (blockIdx.x & 31) << 1;

  // ---- stage x rows h0-1..h0+2 (replicate-clamped) into [r][w][p][c2] bf16,
  //      folding per-(r,p,w) fp32 min/max (ref-accurate) into the same pass.
  //      Thread (r = tid>>6, w = tid&63) covers all 64 channels of its row.
  {
    const int w = tid & 63;
    const int r = tid >> 6;
    const int hr = clampi(h0 - 1 + r, 0, H_ - 1);
    const float* xb = x + ((size_t)b * C_ * H_ * W_) + hr * W_ + w;
    float mn[2] = {3.4e38f, 3.4e38f}, mx[2] = {-3.4e38f, -3.4e38f};
    #pragma unroll
    for (int pm = 0; pm < 8; ++pm) {
      const int p = pm >> 2, m = pm & 3;
      unsigned d[4];
      #pragma unroll
      for (int e = 0; e < 4; ++e) {
        const int c2a = m * 8 + 2 * e;
        const float f0 = xb[(2 * c2a + p) * (H_ * W_)];
        const float f1 = xb[(2 * (c2a + 1) + p) * (H_ * W_)];
        mn[p] = fminf(mn[p], fminf(f0, f1));
        mx[p] = fmaxf(mx[p], fmaxf(f0, f1));
        d[e] = (unsigned)f2bf(f0) | ((unsigned)f2bf(f1) << 16);
      }
      *(uint4*)(smem + XT_OFF + (r * 64 + w) * 144 + p * 64 + m * 16) =
          make_uint4(d[0], d[1], d[2], d[3]);
    }
    ((float*)(smem + PMIN_OFF))[(0 * 4 + r) * 64 + w] = mn[0];
    ((float*)(smem + PMIN_OFF))[(1 * 4 + r) * 64 + w] = mn[1];
    ((float*)(smem + PMAX_OFF))[(0 * 4 + r) * 64 + w] = mx[0];
    ((float*)(smem + PMAX_OFF))[(1 * 4 + r) * 64 + w] = mx[1];
  }
  __syncthreads();

  // ---- s-pass: 3x3 window reduce -> (s+eps), 1/(s+eps) per (row hh, p, w)
  {
    const int hh = tid >> 7, p = (tid >> 6) & 1, w = tid & 63;
    const float* pmin = (const float*)(smem + PMIN_OFF);
    const float* pmax = (const float*)(smem + PMAX_OFF);
    float mn = 3.4e38f, mx = -3.4e38f;
    #pragma unroll
    for (int r = 0; r < 3; ++r) {
      #pragma unroll
      for (int dw = -1; dw <= 1; ++dw) {
        const int wc = clampi(w + dw, 0, W_ - 1);
        mn = fminf(mn, pmin[(p * 4 + (hh + r)) * 64 + wc]);
        mx = fmaxf(mx, pmax[(p * 4 + (hh + r)) * 64 + wc]);
      }
    }
    const float sv = (mx - mn) + EPS;
    ((float*)(smem + SEPS_OFF))[(hh * 2 + p) * 64 + w] = sv;
    ((float*)(smem + SINV_OFF))[(hh * 2 + p) * 64 + w] = 1.0f / sv;
  }
  __syncthreads();

  // ---- MFMA main loop: weights in VGPRs, iterate by x-row so each B-frag
  //      set (3 j-shifts x 4 n-tiles) feeds both output rows.
  const int o0  = wv * 16;
  const int l15 = lane & 15;
  const int q   = lane >> 4;

  const f32x4 zero = {0.0f, 0.0f, 0.0f, 0.0f};
  f32x4 acc[2][2][4];                 // [p][hh][nt]
  #pragma unroll
  for (int p = 0; p < 2; ++p)
    #pragma unroll
    for (int hh = 0; hh < 2; ++hh)
      #pragma unroll
      for (int nt = 0; nt < 4; ++nt) acc[p][hh][nt] = zero;

  #pragma unroll
  for (int p = 0; p < 2; ++p) {
    bf16x8 af[9];                     // A[m=o][k=c2], m=lane&15, k=q*8+j
    #pragma unroll
    for (int t9 = 0; t9 < 9; ++t9)
      af[t9] = *(const bf16x8*)(Wt + ((t9 * 2 + p) * 64 + o0 + l15) * 32 + q * 8);
    #pragma unroll
    for (int xr = 0; xr < 4; ++xr) {
      #pragma unroll
      for (int nt = 0; nt < 4; ++nt) {
        bf16x8 bfr[3];                // B[k=c2][n=w], n=lane&15, k=q*8+j
        #pragma unroll
        for (int j = 0; j < 3; ++j) {
          const int wc = clampi(nt * 16 + l15 + j - 1, 0, W_ - 1);
          bfr[j] = *(const bf16x8*)(smem + XT_OFF + (xr * 64 + wc) * 144 + p * 64 + q * 16);
        }
        #pragma unroll
        for (int hh = 0; hh < 2; ++hh) {
          const int i = xr - hh;      // kernel row offset; valid 0..2
          if (i >= 0 && i < 3) {
            #pragma unroll
            for (int j = 0; j < 3; ++j)
              acc[p][hh][nt] = __builtin_amdgcn_mfma_f32_16x16x32_bf16(
                  af[i * 3 + j], bfr[j], acc[p][hh][nt], 0, 0, 0);
          }
        }
      }
    }
  }

  // ---- epilogue: combine parities, bias, leaky-relu, re-scale, store fp32 ----
  // D layout: col(w) = lane&15, row(o-within-16) = (lane>>4)*4 + reg
  const float* sinv = (const float*)(smem + SINV_OFF);
  const float* seps = (const float*)(smem + SEPS_OFF);
  #pragma unroll
  for (int hh = 0; hh < 2; ++hh) {
    #pragma unroll
    for (int nt = 0; nt < 4; ++nt) {
      const int wpx = nt * 16 + l15;
      const float s0 = sinv[(hh * 2 + 0) * 64 + wpx];
      const float s1 = sinv[(hh * 2 + 1) * 64 + wpx];
      const float se0 = seps[(hh * 2 + 0) * 64 + wpx];
      const float se1 = seps[(hh * 2 + 1) * 64 + wpx];
      #pragma unroll
      for (int reg = 0; reg < 4; ++reg) {
        const int o = o0 + q * 4 + reg;
        float v = acc[0][hh][nt][reg] * s0 + acc[1][hh][nt][reg] * s1 + bias[o];
        v = v >= 0.0f ? v : SLOPE * v;
        v *= (o & 1) ? se1 : se0;
        out[((b * O_ + o) * H_ + (h0 + hh)) * W_ + wpx] = v;
      }
    }
  }
}

extern "C" void kernel_launch(void* const* d_in, const int* in_sizes, int n_in,
                              void* d_out, int out_size, void* d_ws, size_t ws_size,
                              hipStream_t stream) {
  const float* x    = (const float*)d_in[0];
  const float* Wsrc = (const float*)d_in[1];
  const float* bias = (const float*)d_in[2];
  float* out = (float*)d_out;
  unsigned short* Wt = (unsigned short*)d_ws;   // 73,728 B bf16 weight scratch

  wtransform_kernel<<<144, 256, 0, stream>>>(Wsrc, Wt);
  conv_main_kernel<<<512, 256, 0, stream>>>(x, Wt, bias, out);
}